// Round 12
// baseline (268.706 us; speedup 1.0000x reference)
//
#include <hip/hip_runtime.h>
#include <cstddef>

#define BB 128

typedef unsigned short u16;
typedef __attribute__((ext_vector_type(8))) short short8;
typedef __attribute__((ext_vector_type(4))) short short4v;
typedef __attribute__((ext_vector_type(4))) float f32x4;

constexpr int ilog2c(int v){ return v<=1 ? 0 : 1+ilog2c(v>>1); }

__device__ __forceinline__ u16 f2b(float f){
  union {float f; unsigned u;} x; x.f = f;
  unsigned u = x.u + 0x7fffu + ((x.u>>16)&1u);
  return (u16)(u>>16);
}
__device__ __forceinline__ float b2f(u16 h){
  union {unsigned u; float f;} x; x.u = ((unsigned)h)<<16;
  return x.f;
}

#define GLOAD_LDS16(gsrc, ldsdst) \
  __builtin_amdgcn_global_load_lds((const __attribute__((address_space(1))) void*)(gsrc), \
      (__attribute__((address_space(3))) void*)(ldsdst), 16, 0, 0)

// ============ implicit-GEMM conv: 128x128 tile, 512 thr, dbuf LDS + prefetch ============
// GRID: blockIdx.x = m-tile (A-panel pairs share an XCD), blockIdx.y = n-tile, z = k-split
// STORE: 0 = bf16 [M][OC]; 1 = lrelu -> padded bf16; 3 = bf16 partial [KSPLIT][M][OC]
template<int IC, int OC, int OH, int STORE, int KSPLIT=1>
__global__ __launch_bounds__(512) void convmm2(
    const u16* __restrict__ xp, const u16* __restrict__ wtT, void* __restrict__ yv)
{
  constexpr int OW = OH, S = OH*OW;
  constexpr int IHp = 2*OH+2, IWp = 2*OW+2;
  constexpr int KT = 16*IC;
  constexpr int KTS = KT / KSPLIT;
  constexpr int NT = KTS / 64;
  constexpr int LS = ilog2c(S), LOW = ilog2c(OW), L4 = ilog2c(4*IC);
  __shared__ u16 As[2*128*64];
  __shared__ u16 Bs[2*128*64];
  const int tid = threadIdx.x;
  const int m0 = blockIdx.x*128;
  const int n0 = blockIdx.y*128;
  const int kbase = (KSPLIT>1) ? blockIdx.z*KTS : 0;
  const int wave = tid>>6, l = tid&63;
  const int wm = wave>>1, wn = wave&1;

  size_t abase[2]; int au[2];
  #pragma unroll
  for (int t=0;t<2;++t){
    int unit = tid + t*512;
    int r = unit>>3, us = unit&7;
    au[t] = us ^ (r&7);
    int p = m0 + r;
    int b = p >> LS, s = p & (S-1);
    int oh = s >> LOW, ow = s & (OW-1);
    abase[t] = ((size_t)(b*IHp + 2*oh)*IWp + 2*ow)*IC;
  }
  const u16* bsrc[2];
  #pragma unroll
  for (int t=0;t<2;++t){
    int unit = tid + t*512;
    int r = unit>>3, us = unit&7;
    bsrc[t] = wtT + (size_t)(n0+r)*KT + (size_t)(us ^ (r&7))*8;
  }

  auto stage = [&](int half, int k0){
    #pragma unroll
    for (int t=0;t<2;++t){
      int k = k0 + au[t]*8;
      int kh = k >> L4, koff = k & (4*IC-1);
      GLOAD_LDS16(xp + abase[t] + (size_t)kh*IWp*IC + koff,
                  &As[half*8192 + (size_t)(t*512 + wave*64)*8]);
    }
    #pragma unroll
    for (int t=0;t<2;++t){
      GLOAD_LDS16(bsrc[t] + k0, &Bs[half*8192 + (size_t)(t*512 + wave*64)*8]);
    }
  };

  f32x4 acc[2][4] = {};

  stage(0, kbase);
  __syncthreads();
  int cur = 0;
  for (int t=0; t<NT; ++t){
    if (t+1 < NT) stage(cur^1, kbase + (t+1)*64);
    #pragma unroll
    for (int kk=0;kk<2;++kk){
      short8 af[2], bfm[4];
      #pragma unroll
      for (int mi=0;mi<2;++mi){
        int row = wm*32 + mi*16 + (l&15);
        int u = (kk*4 + (l>>4)) ^ (row&7);
        af[mi] = *(const short8*)(&As[cur*8192 + row*64 + u*8]);
      }
      #pragma unroll
      for (int ni=0;ni<4;++ni){
        int row = wn*64 + ni*16 + (l&15);
        int u = (kk*4 + (l>>4)) ^ (row&7);
        bfm[ni] = *(const short8*)(&Bs[cur*8192 + row*64 + u*8]);
      }
      #pragma unroll
      for (int mi=0;mi<2;++mi)
        #pragma unroll
        for (int ni=0;ni<4;++ni)
          acc[mi][ni] = __builtin_amdgcn_mfma_f32_16x16x32_bf16(af[mi], bfm[ni], acc[mi][ni], 0,0,0);
    }
    __syncthreads();
    cur ^= 1;
  }
  #pragma unroll
  for (int mi=0;mi<2;++mi){
    #pragma unroll
    for (int ni=0;ni<4;++ni){
      #pragma unroll
      for (int r=0;r<4;++r){
        int row = m0 + wm*32 + mi*16 + (l>>4)*4 + r;
        int col = n0 + wn*64 + ni*16 + (l&15);
        float v = acc[mi][ni][r];
        if (STORE==0){
          ((u16*)yv)[(size_t)row*OC + col] = f2b(v);
        } else if (STORE==1){
          v = v>=0.f ? v : 0.2f*v;
          int b = row>>LS, s = row&(S-1);
          int oh = s>>LOW, ow = s&(OW-1);
          ((u16*)yv)[((size_t)(b*(OH+2) + oh+1)*(OW+2) + ow+1)*OC + col] = f2b(v);
        } else {
          ((u16*)yv)[((size_t)blockIdx.z*(BB*S) + row)*OC + col] = f2b(v);
        }
      }
    }
  }
}

// ============ K-split GEMM, M=128: A bf16 gload_lds dbuf; B bf16 gload_lds OR fp32 reg-convert ============
// P16: partials stored as bf16 (u16) instead of fp32
template<int B_FP32, int P16>
__global__ __launch_bounds__(256) void gemm128_split(
    const u16* __restrict__ A, const void* __restrict__ Bsrc,
    void* __restrict__ part, int K, int kchunk)
{
  __shared__ u16 As[2*128*64];
  __shared__ u16 Bs[2*64*64];
  const int tid = threadIdx.x;
  const int n0 = blockIdx.x*64;
  const int kbase = blockIdx.y*kchunk;
  const int wave = tid>>6, l = tid&63;
  const u16* asrc[4];
  #pragma unroll
  for (int t=0;t<4;++t){
    int unit = tid + t*256, r = unit>>3, us = unit&7;
    asrc[t] = A + (size_t)r*K + (size_t)(us ^ (r&7))*8;
  }
  const float* bf32[4]; int bdst32[4];
  const u16* b16[2];
  if (B_FP32){
    const float* Bf = (const float*)Bsrc;
    #pragma unroll
    for (int t=0;t<4;++t){
      int unit = tid + t*256;
      int r = unit>>4, u4 = unit&15;
      int u = u4>>1, hf = u4&1;
      int us = u ^ (r&7);
      bf32[t] = Bf + (size_t)(n0+r)*K + u4*4;
      bdst32[t] = r*64 + us*8 + hf*4;
    }
  } else {
    const u16* Bb = (const u16*)Bsrc;
    #pragma unroll
    for (int t=0;t<2;++t){
      int unit = tid + t*256, r = unit>>3, us = unit&7;
      b16[t] = Bb + (size_t)(n0+r)*K + (size_t)(us ^ (r&7))*8;
    }
  }

  auto stageA = [&](int half, int k0){
    #pragma unroll
    for (int t=0;t<4;++t)
      GLOAD_LDS16(asrc[t] + k0, &As[half*8192 + (size_t)(t*256 + wave*64)*8]);
  };
  auto stageB16 = [&](int half, int k0){
    #pragma unroll
    for (int t=0;t<2;++t)
      GLOAD_LDS16(b16[t] + k0, &Bs[half*4096 + (size_t)(t*256 + wave*64)*8]);
  };
  float4 breg[4];
  auto loadB32 = [&](int k0){
    #pragma unroll
    for (int t=0;t<4;++t) breg[t] = *(const float4*)(bf32[t] + k0);
  };
  auto writeB32 = [&](int half){
    #pragma unroll
    for (int t=0;t<4;++t){
      short4v o; o[0]=(short)f2b(breg[t].x); o[1]=(short)f2b(breg[t].y);
      o[2]=(short)f2b(breg[t].z); o[3]=(short)f2b(breg[t].w);
      *(short4v*)(&Bs[half*4096 + bdst32[t]]) = o;
    }
  };

  f32x4 acc[2][4] = {};
  const int NT = kchunk >> 6;
  stageA(0, kbase);
  if (B_FP32){ loadB32(kbase); writeB32(0); } else stageB16(0, kbase);
  __syncthreads();
  int cur = 0;
  for (int t=0;t<NT;++t){
    const int k0 = kbase + t*64;
    if (t+1 < NT){
      stageA(cur^1, k0+64);
      if (B_FP32) loadB32(k0+64);
      else stageB16(cur^1, k0+64);
    }
    #pragma unroll
    for (int kk=0;kk<2;++kk){
      short8 af[2], bfm[4];
      #pragma unroll
      for (int mi=0;mi<2;++mi){
        int row = wave*32 + mi*16 + (l&15);
        int u = (kk*4 + (l>>4)) ^ (row&7);
        af[mi] = *(const short8*)(&As[cur*8192 + row*64 + u*8]);
      }
      #pragma unroll
      for (int ni=0;ni<4;++ni){
        int row = ni*16 + (l&15);
        int u = (kk*4 + (l>>4)) ^ (row&7);
        bfm[ni] = *(const short8*)(&Bs[cur*4096 + row*64 + u*8]);
      }
      #pragma unroll
      for (int mi=0;mi<2;++mi)
        #pragma unroll
        for (int ni=0;ni<4;++ni)
          acc[mi][ni] = __builtin_amdgcn_mfma_f32_16x16x32_bf16(af[mi], bfm[ni], acc[mi][ni], 0,0,0);
    }
    if (B_FP32 && t+1 < NT) writeB32(cur^1);
    __syncthreads();
    cur ^= 1;
  }
  #pragma unroll
  for (int mi=0;mi<2;++mi){
    #pragma unroll
    for (int ni=0;ni<4;++ni){
      #pragma unroll
      for (int r=0;r<4;++r){
        int m = wave*32 + mi*16 + (l>>4)*4 + r;
        int n = n0 + ni*16 + (l&15);
        size_t off = ((size_t)blockIdx.y*128 + m)*4096 + n;
        if (P16) ((u16*)part)[off] = f2b(acc[mi][ni][r]);
        else     ((float*)part)[off] = acc[mi][ni][r];
      }
    }
  }
}

// ============ border zeroing helper ============
template<int Hp, int C>
__device__ __forceinline__ void zb_border(u16* __restrict__ buf, int idx, int count){
  if (idx >= count) return;
  constexpr int NP = 4*Hp - 4;
  constexpr int PC = NP*C;
  int b = idx / PC;
  int rem = idx - b*PC;
  int p = rem >> ilog2c(C);
  int c = rem & (C-1);
  int h, w;
  if (p < Hp){ h = 0; w = p; }
  else if (p < 2*Hp){ h = Hp-1; w = p - Hp; }
  else { int q = p - 2*Hp; h = 1 + (q>>1); w = (q&1) ? (Hp-1) : 0; }
  buf[(((size_t)b*Hp + h)*Hp + w)*C + c] = 0;
}

// reduce 16 bf16 FC partials (in y2 region — NO overlap with xp1/xp2) -> relu -> xp0 ch3;
// plus xp1/xp2 border zeroing (disjoint regions, race-free)
__global__ __launch_bounds__(256) void fc_reduce_zb(const u16* __restrict__ part,
                                                    u16* __restrict__ xp0,
                                                    u16* __restrict__ xp1, u16* __restrict__ xp2)
{
  const int blk = blockIdx.x, tid = threadIdx.x;
  if (blk < 2048){
    int idx = blk*256 + tid;
    float s = 0.f;
    #pragma unroll
    for (int i=0;i<16;++i) s += b2f(part[(size_t)i*524288 + idx]);
    float v = fmaxf(s, 0.f);
    int m = idx>>12, n = idx&4095;
    int h = n>>6, w2 = n&63;
    xp0[((size_t)(m*66 + h+1)*66 + w2+1)*4 + 3] = f2b(v);
  } else if (blk < 10496){
    zb_border<34,128>(xp1, (blk-2048)*256 + tid, 2162688);
  } else {
    zb_border<18,256>(xp2, (blk-10496)*256 + tid, 2228224);
  }
}

// reduce 8 fp32 partials of [128][4096] -> Ms
__global__ __launch_bounds__(256) void reduce_ms(const float* __restrict__ part, float* __restrict__ outv)
{
  int idx = blockIdx.x*256 + threadIdx.x;
  float s = 0.f;
  #pragma unroll
  for (int i=0;i<8;++i) s += part[(size_t)i*524288 + idx];
  outv[idx] = s;
}

// fused: reduce NS bf16 partials -> bf16 y, AND per-block BN stats partials
template<int NS, int C>
__global__ __launch_bounds__(256) void reduce_bn(
    const u16* __restrict__ part, u16* __restrict__ y,
    float* __restrict__ stats, int Mblk, int Mtot)
{
  constexpr int CU = C/8, NR = 256/CU, LCU = ilog2c(CU);
  __shared__ float red[NR*C];
  const int cu = threadIdx.x & (CU-1);
  const int rg = threadIdx.x >> LCU;
  const int base = blockIdx.x*Mblk;
  float s[8] = {}, ss[8] = {};
  for (int p = base+rg; p < base+Mblk; p += NR){
    float a8[8];
    #pragma unroll
    for (int j=0;j<8;++j) a8[j]=0.f;
    #pragma unroll
    for (int i=0;i<NS;++i){
      short8 v = *(const short8*)(part + ((size_t)i*Mtot + p)*C + cu*8);
      #pragma unroll
      for (int j=0;j<8;++j) a8[j] += b2f((u16)v[j]);
    }
    u16 o[8];
    #pragma unroll
    for (int j=0;j<8;++j){
      o[j] = f2b(a8[j]);
      float vb = b2f(o[j]);
      s[j]+=vb; ss[j]+=vb*vb;
    }
    *(short8*)(y + (size_t)p*C + cu*8) = *(short8*)o;
  }
  #pragma unroll
  for (int j=0;j<8;++j) red[rg*C + cu*8 + j] = s[j];
  __syncthreads();
  for (int c=threadIdx.x; c<C; c+=256){
    float t=0.f;
    #pragma unroll
    for (int r2=0;r2<NR;++r2) t += red[r2*C+c];
    stats[blockIdx.x*512 + c] = t;
  }
  __syncthreads();
  #pragma unroll
  for (int j=0;j<8;++j) red[rg*C + cu*8 + j] = ss[j];
  __syncthreads();
  for (int c=threadIdx.x; c<C; c+=256){
    float t=0.f;
    #pragma unroll
    for (int r2=0;r2<NR;++r2) t += red[r2*C+c];
    stats[131072 + blockIdx.x*512 + c] = t;
  }
}

// reduce conv5 bf16 partials [32][512][256] -> d_out feat (fp32, permuted) + featb (bf16)
__global__ __launch_bounds__(256) void conv5_reduce(const u16* __restrict__ part,
                                                    float* __restrict__ out, u16* __restrict__ featb)
{
  int idx = blockIdx.x*256 + threadIdx.x;
  float s = 0.f;
  #pragma unroll
  for (int i=0;i<32;++i) s += b2f(part[(size_t)i*131072 + idx]);
  int row = idx>>8, col = idx&255;
  int b = row>>2, sp = row&3;
  out[(size_t)b*1280 + col*4 + sp] = s;
  featb[(size_t)b*1024 + col*4 + sp] = f2b(s);
}

// ============ mega-prologue ============
template<int IC, int ICP>
__device__ __forceinline__ void repack_dev(const float* __restrict__ w, u16* __restrict__ wt,
                                           int oc, int tid, float* ls){
  for (int i=tid; i<IC*16; i+=256){
    int ic = i>>4, khkw = i&15;
    ls[ic*17+khkw] = w[(size_t)oc*IC*16 + i];
  }
  __syncthreads();
  constexpr int KT = 16*ICP;
  constexpr int LP = ilog2c(ICP);
  for (int k=tid; k<KT; k+=256){
    int khkw = k >> LP, ic = k & (ICP-1);
    float v = (ic<IC) ? ls[ic*17+khkw] : 0.f;
    wt[(size_t)oc*KT + k] = f2b(v);
  }
}

__device__ __forceinline__ void transpose_dev(const float* __restrict__ T, u16* __restrict__ Tt,
                                              int idx, int tid, float* tile){
  int bx = idx & 127, by = idx >> 7;
  int kb = by*32, nb = bx*32;
  int tx = tid&31, ty = tid>>5;
  #pragma unroll
  for (int i=0;i<32;i+=8)
    tile[(ty+i)*33 + tx] = T[(size_t)(kb+ty+i)*4096 + nb+tx];
  __syncthreads();
  #pragma unroll
  for (int i=0;i<32;i+=8)
    Tt[(size_t)(nb+ty+i)*1024 + kb+tx] = f2b(tile[tx*33 + ty+i]);
}

__global__ __launch_bounds__(256) void prep_all(
    const float* __restrict__ w1, const float* __restrict__ w2, const float* __restrict__ w3,
    const float* __restrict__ w4, const float* __restrict__ w5, const float* __restrict__ T,
    const float* __restrict__ wvec, const float* __restrict__ img,
    u16* wt1T, u16* wt2T, u16* wt3T, u16* wt4T, u16* wt5T, u16* Tt, u16* wvb, u16* xp0)
{
  __shared__ float ls[512*17];
  const int blk = blockIdx.x, tid = threadIdx.x;
  if (blk < 128)        repack_dev<4,4>(w1, wt1T, blk, tid, ls);
  else if (blk < 384)   repack_dev<128,128>(w2, wt2T, blk-128, tid, ls);
  else if (blk < 640)   repack_dev<256,256>(w3, wt3T, blk-384, tid, ls);
  else if (blk < 1152)  repack_dev<256,256>(w4, wt4T, blk-640, tid, ls);
  else if (blk < 1408)  repack_dev<512,512>(w5, wt5T, blk-1152, tid, ls);
  else if (blk < 5504)  transpose_dev(T, Tt, blk-1408, tid, ls);
  else if (blk < 7552){ int i = (blk-5504)*256 + tid; wvb[i] = f2b(wvec[i]); }
  else if (blk < 9600){
    int idx = (blk-7552)*256 + tid;
    int b = idx>>12, s = idx&4095;
    int h = s>>6, w = s&63;
    short4v o;
    o[0] = (short)f2b(img[(size_t)(b*3+0)*4096 + s]);
    o[1] = (short)f2b(img[(size_t)(b*3+1)*4096 + s]);
    o[2] = (short)f2b(img[(size_t)(b*3+2)*4096 + s]);
    o[3] = 0;
    *(short4v*)(xp0 + ((size_t)(b*66 + h+1)*66 + w+1)*4) = o;
  } else {
    zb_border<66,4>(xp0, (blk-9600)*256 + tid, 133120);
  }
}

// ============ BN stats (reads y bf16), separate finalize dispatch (coherence-safe) ============
template<int C>
__global__ __launch_bounds__(256) void bn_stats2(const u16* __restrict__ y, float* __restrict__ stats, int Mblk){
  constexpr int CU = C/8, NR = 256/CU, LCU = ilog2c(CU);
  __shared__ float red[NR*C];
  const int cu = threadIdx.x & (CU-1);
  const int rg = threadIdx.x >> LCU;
  const int base = blockIdx.x*Mblk;
  float s[8] = {}, ss[8] = {};
  for (int p = base+rg; p < base+Mblk; p += NR){
    short8 v = *(const short8*)(y + (size_t)p*C + cu*8);
    #pragma unroll
    for (int j=0;j<8;++j){ float f=b2f((u16)v[j]); s[j]+=f; ss[j]+=f*f; }
  }
  #pragma unroll
  for (int j=0;j<8;++j) red[rg*C + cu*8 + j] = s[j];
  __syncthreads();
  for (int c=threadIdx.x; c<C; c+=256){
    float t=0.f;
    #pragma unroll
    for (int r2=0;r2<NR;++r2) t += red[r2*C+c];
    stats[blockIdx.x*512 + c] = t;
  }
  __syncthreads();
  #pragma unroll
  for (int j=0;j<8;++j) red[rg*C + cu*8 + j] = ss[j];
  __syncthreads();
  for (int c=threadIdx.x; c<C; c+=256){
    float t=0.f;
    #pragma unroll
    for (int r2=0;r2<NR;++r2) t += red[r2*C+c];
    stats[131072 + blockIdx.x*512 + c] = t;
  }
}

template<int C>
__global__ __launch_bounds__(C) void bn_finalize(float* __restrict__ stats, const float* __restrict__ g,
                                                 const float* __restrict__ be, float cnt){
  int c = threadIdx.x;
  float s=0.f, ss=0.f;
  for (int b=0;b<256;++b){ s += stats[b*512+c]; ss += stats[131072 + b*512+c]; }
  float m = s/cnt;
  float var = ss/cnt - m*m;
  float A = rsqrtf(var + 1e-5f)*g[c];
  stats[262144 + c] = A;
  stats[262144 + 512 + c] = be[c] - m*A;
}

template<int C, int OH>
__device__ __forceinline__ void bn_apply_body(const u16* __restrict__ y, const float* __restrict__ stats,
                                              u16* __restrict__ xp, int idx){
  constexpr int S = OH*OH, LS = ilog2c(S), LOW = ilog2c(OH);
  constexpr int CU = C/8, LCU = ilog2c(CU);
  int p = idx >> LCU, cu = idx & (CU-1);
  short8 v8 = *(const short8*)(y + (size_t)p*C + cu*8);
  const float* Ap = stats + 262144;
  const float* Bp = stats + 262144 + 512;
  u16 o[8];
  #pragma unroll
  for (int j=0;j<8;++j){
    float v = b2f((u16)v8[j])*Ap[cu*8+j] + Bp[cu*8+j];
    o[j] = f2b(v>=0.f ? v : 0.2f*v);
  }
  int b = p>>LS, s = p&(S-1), oh = s>>LOW, ow = s&(OH-1);
  *(short8*)(xp + ((size_t)(b*(OH+2)+oh+1)*(OH+2)+ow+1)*C + cu*8) = *(short8*)o;
}

template<int C, int OH>
__global__ __launch_bounds__(256) void bn_apply(const u16* __restrict__ y, const float* __restrict__ stats,
                                                u16* __restrict__ xp){
  bn_apply_body<C,OH>(y, stats, xp, blockIdx.x*256 + threadIdx.x);
}

// BN2 apply + xp3/xp4 border zeroing (xp1 region dead once this runs)
__global__ __launch_bounds__(256) void bn_apply2_zb(const u16* __restrict__ y, const float* __restrict__ stats,
                                                    u16* __restrict__ xp, u16* xp3, u16* xp4){
  const int blk = blockIdx.x, tid = threadIdx.x;
  if (blk < 4096)       bn_apply_body<256,16>(y, stats, xp, blk*256 + tid);
  else if (blk < 8704)  zb_border<10,256>(xp3, (blk-4096)*256 + tid, 1179648);
  else                  zb_border<6,512>(xp4, (blk-8704)*256 + tid, 1310720);
}

// ============ minibatch discrimination: single kernel, 1024 threads ============
__global__ __launch_bounds__(1024) void mbd_fused(const float* __restrict__ Ms, float* __restrict__ out)
{
  __shared__ float red[4][256];
  const int i = blockIdx.x;
  const int o = threadIdx.x & 255;
  const int jg = threadIdx.x >> 8;      // 0..3, each covers 32 j
  float mi[16];
  #pragma unroll
  for (int u = 0; u < 4; ++u) {
    float4 v = *(const float4*)&Ms[(size_t)i * 4096 + o * 16 + u * 4];
    mi[u*4+0]=v.x; mi[u*4+1]=v.y; mi[u*4+2]=v.z; mi[u*4+3]=v.w;
  }
  float acc = 0.f;
  for (int j = jg*32; j < jg*32 + 32; ++j) {
    float d = 0.f;
    #pragma unroll
    for (int u = 0; u < 4; ++u) {
      float4 v = *(const float4*)&Ms[(size_t)j * 4096 + o * 16 + u * 4];
      d += fabsf(mi[u*4+0]-v.x) + fabsf(mi[u*4+1]-v.y) + fabsf(mi[u*4+2]-v.z) + fabsf(mi[u*4+3]-v.w);
    }
    acc += __expf(-d);
  }
  red[jg][o] = acc;
  __syncthreads();
  if (jg == 0)
    out[(size_t)i*1280 + 1024 + o] = red[0][o] + red[1][o] + red[2][o] + red[3][o];
}

__global__ void ws_too_small(float* out, int n){
  int idx = blockIdx.x*256+threadIdx.x;
  if (idx<n) out[idx] = -777.0f;
}

extern "C" void kernel_launch(void* const* d_in, const int* in_sizes, int n_in,
                              void* d_out, int out_size, void* d_ws, size_t ws_size,
                              hipStream_t stream)
{
  const float* image = (const float*)d_in[0];
  const float* wvec  = (const float*)d_in[1];
  const float* fc_w  = (const float*)d_in[2];
  const float* w1    = (const float*)d_in[3];
  const float* w2    = (const float*)d_in[4];
  const float* w3    = (const float*)d_in[5];
  const float* w4    = (const float*)d_in[6];
  const float* w5    = (const float*)d_in[7];
  const float* g2    = (const float*)d_in[8];
  const float* b2    = (const float*)d_in[9];
  const float* g3    = (const float*)d_in[10];
  const float* b3    = (const float*)d_in[11];
  const float* g4    = (const float*)d_in[12];
  const float* b4    = (const float*)d_in[13];
  const float* T     = (const float*)d_in[14];
  float* out = (float*)d_out;
  char* wsb = (char*)d_ws;

  const size_t NEED = 105816064ull;
  if (ws_size < NEED) {
    ws_too_small<<<(out_size + 255)/256, 256, 0, stream>>>(out, out_size);
    return;
  }

  // region map (lifetime-packed):
  u16* xp1   = (u16*)(wsb + 0);
  u16* y3    = (u16*)(wsb + 0);
  u16* xp3   = (u16*)(wsb + 4194304);
  u16* y4    = (u16*)(wsb + 10747904);
  u16* xp4   = (u16*)(wsb + 12845056);
  float* Ms  = (float*)(wsb + 17563648);
  u16* featb = (u16*)(wsb + 19660800);
  float* stats = (float*)(wsb + 19922944);
  u16* xp2   = (u16*)(wsb + 37879808);
  u16* c4part = (u16*)(wsb + 37879808);        // conv4 bf16 partials [4][2048][512] = 8.4 MB
  u16* c5part = (u16*)(wsb + 37879808);        // conv5 bf16 partials [32][512][256] = 8.4 MB
  u16* y2    = (u16*)(wsb + 59113472);
  u16* gpartF = (u16*)(wsb + 59113472);        // FC bf16 partials [16][128][4096] = 16.77 MB (y2 region, dead pre-conv2; NO xp2 overlap)
  float* gpartM = (float*)(wsb + 59113472);    // Ms fp32 partials [8][128][4096] (y2 region, dead post-BN2-apply)
  u16* c3part = (u16*)(wsb + 59113472);        // conv3 bf16 partials [2][8192][256] = 8.4 MB
  u16* xp0   = (u16*)(wsb + 75890688);
  u16* wt1T  = (u16*)(wsb + 84811776);
  u16* wt2T  = (u16*)(wsb + 84844544);
  u16* wt3T  = (u16*)(wsb + 85893120);
  u16* wt4T  = (u16*)(wsb + 87990272);
  u16* wt5T  = (u16*)(wsb + 92184576);
  u16* Tt    = (u16*)(wsb + 96378880);
  u16* wvb   = (u16*)(wsb + 104767488);

  // 1. mega-prologue
  prep_all<<<10120, 256, 0, stream>>>(w1, w2, w3, w4, w5, T, wvec, image,
                                      wt1T, wt2T, wt3T, wt4T, wt5T, Tt, wvb, xp0);

  // 2-3. FC (fp32 B reg-convert, 16-way K-split, bf16 partials in y2 region) -> reduce -> relu -> xp0 ch3 (+ borders)
  gemm128_split<1,1><<<dim3(64,16), 256, 0, stream>>>(wvb, fc_w, gpartF, 4096, 256);
  fc_reduce_zb<<<19200, 256, 0, stream>>>(gpartF, xp0, xp1, xp2);

  // 4. conv1 + lrelu -> xp1 (IC=4 native)
  convmm2<4,128,32,1><<<dim3(1024,1), 512, 0, stream>>>(xp0, wt1T, xp1);
  // 5. conv2 -> y2 (overwrites gpartF, dead)
  convmm2<128,256,16,0><<<dim3(256,2), 512, 0, stream>>>(xp1, wt2T, y2);

  // 6-8. BN2 stats -> finalize -> apply + xp3/xp4 borders
  bn_stats2<256><<<256, 256, 0, stream>>>(y2, stats, 128);
  bn_finalize<256><<<1, 256, 0, stream>>>(stats, g2, b2, 32768.f);
  bn_apply2_zb<<<13824, 256, 0, stream>>>(y2, stats, xp2, xp3, xp4);

  // 9-12. conv3 (KSPLIT=2, bf16 partials in y2 region) -> reduce+stats -> finalize -> apply
  convmm2<256,256,8,3,2><<<dim3(64,2,2), 512, 0, stream>>>(xp2, wt3T, c3part);
  reduce_bn<2,256><<<256, 256, 0, stream>>>(c3part, y3, stats, 32, 8192);
  bn_finalize<256><<<1, 256, 0, stream>>>(stats, g3, b3, 8192.f);
  bn_apply<256,8><<<1024, 256, 0, stream>>>(y3, stats, xp3);

  // 13-16. conv4 (KSPLIT=4, bf16 partials in xp2 region) -> reduce+stats -> finalize -> apply
  convmm2<256,512,4,3,4><<<dim3(16,4,4), 512, 0, stream>>>(xp3, wt4T, c4part);
  reduce_bn<4,512><<<256, 256, 0, stream>>>(c4part, y4, stats, 8, 2048);
  bn_finalize<512><<<1, 512, 0, stream>>>(stats, g4, b4, 2048.f);
  bn_apply<512,4><<<512, 256, 0, stream>>>(y4, stats, xp4);

  // 17-18. conv5 (KSPLIT=32, bf16 partials) -> reduce -> out feat + featb
  convmm2<512,256,2,3,32><<<dim3(4,2,32), 512, 0, stream>>>(xp4, wt5T, c5part);
  conv5_reduce<<<512, 256, 0, stream>>>(c5part, out, featb);

  // 19-20. Ms = feat @ T (K-split 8, fp32 partials in y2 region) -> Ms
  gemm128_split<0,0><<<dim3(64,8), 256, 0, stream>>>(featb, Tt, gpartM, 1024, 128);
  reduce_ms<<<2048, 256, 0, stream>>>(gpartM, Ms);

  // 21. mbd single kernel
  mbd_fused<<<128, 1024, 0, stream>>>(Ms, out);
}

// Round 13
// 246.824 us; speedup vs baseline: 1.0887x; 1.0887x over previous
//
#include <hip/hip_runtime.h>
#include <cstddef>

#define BB 128

typedef unsigned short u16;
typedef __attribute__((ext_vector_type(8))) short short8;
typedef __attribute__((ext_vector_type(4))) short short4v;
typedef __attribute__((ext_vector_type(4))) float f32x4;

constexpr int ilog2c(int v){ return v<=1 ? 0 : 1+ilog2c(v>>1); }

__device__ __forceinline__ u16 f2b(float f){
  union {float f; unsigned u;} x; x.f = f;
  unsigned u = x.u + 0x7fffu + ((x.u>>16)&1u);
  return (u16)(u>>16);
}
__device__ __forceinline__ float b2f(u16 h){
  union {unsigned u; float f;} x; x.u = ((unsigned)h)<<16;
  return x.f;
}

#define GLOAD_LDS16(gsrc, ldsdst) \
  __builtin_amdgcn_global_load_lds((const __attribute__((address_space(1))) void*)(gsrc), \
      (__attribute__((address_space(3))) void*)(ldsdst), 16, 0, 0)

// ============ implicit-GEMM conv: 128x128 tile, 512 thr, dbuf LDS + prefetch ============
// GRID: blockIdx.x = m-tile (A-panel pairs share an XCD), blockIdx.y = n-tile, z = k-split
// STORE: 0 = bf16 [M][OC]; 1 = lrelu -> padded bf16; 3 = bf16 partial [KSPLIT][M][OC]
// STATS: 1 = also emit per-(m-tile,channel) BN sum/sumsq partials (layout matches bn_finalize)
template<int IC, int OC, int OH, int STORE, int KSPLIT=1, int STATS=0>
__global__ __launch_bounds__(512) void convmm2(
    const u16* __restrict__ xp, const u16* __restrict__ wtT, void* __restrict__ yv,
    float* __restrict__ stats)
{
  constexpr int OW = OH, S = OH*OW;
  constexpr int IHp = 2*OH+2, IWp = 2*OW+2;
  constexpr int KT = 16*IC;
  constexpr int KTS = KT / KSPLIT;
  constexpr int NT = KTS / 64;
  constexpr int LS = ilog2c(S), LOW = ilog2c(OW), L4 = ilog2c(4*IC);
  __shared__ u16 As[2*128*64];
  __shared__ u16 Bs[2*128*64];
  const int tid = threadIdx.x;
  const int m0 = blockIdx.x*128;
  const int n0 = blockIdx.y*128;
  const int kbase = (KSPLIT>1) ? blockIdx.z*KTS : 0;
  const int wave = tid>>6, l = tid&63;
  const int wm = wave>>1, wn = wave&1;

  size_t abase[2]; int au[2];
  #pragma unroll
  for (int t=0;t<2;++t){
    int unit = tid + t*512;
    int r = unit>>3, us = unit&7;
    au[t] = us ^ (r&7);
    int p = m0 + r;
    int b = p >> LS, s = p & (S-1);
    int oh = s >> LOW, ow = s & (OW-1);
    abase[t] = ((size_t)(b*IHp + 2*oh)*IWp + 2*ow)*IC;
  }
  const u16* bsrc[2];
  #pragma unroll
  for (int t=0;t<2;++t){
    int unit = tid + t*512;
    int r = unit>>3, us = unit&7;
    bsrc[t] = wtT + (size_t)(n0+r)*KT + (size_t)(us ^ (r&7))*8;
  }

  auto stage = [&](int half, int k0){
    #pragma unroll
    for (int t=0;t<2;++t){
      int k = k0 + au[t]*8;
      int kh = k >> L4, koff = k & (4*IC-1);
      GLOAD_LDS16(xp + abase[t] + (size_t)kh*IWp*IC + koff,
                  &As[half*8192 + (size_t)(t*512 + wave*64)*8]);
    }
    #pragma unroll
    for (int t=0;t<2;++t){
      GLOAD_LDS16(bsrc[t] + k0, &Bs[half*8192 + (size_t)(t*512 + wave*64)*8]);
    }
  };

  f32x4 acc[2][4] = {};

  stage(0, kbase);
  __syncthreads();
  int cur = 0;
  for (int t=0; t<NT; ++t){
    if (t+1 < NT) stage(cur^1, kbase + (t+1)*64);
    #pragma unroll
    for (int kk=0;kk<2;++kk){
      short8 af[2], bfm[4];
      #pragma unroll
      for (int mi=0;mi<2;++mi){
        int row = wm*32 + mi*16 + (l&15);
        int u = (kk*4 + (l>>4)) ^ (row&7);
        af[mi] = *(const short8*)(&As[cur*8192 + row*64 + u*8]);
      }
      #pragma unroll
      for (int ni=0;ni<4;++ni){
        int row = wn*64 + ni*16 + (l&15);
        int u = (kk*4 + (l>>4)) ^ (row&7);
        bfm[ni] = *(const short8*)(&Bs[cur*8192 + row*64 + u*8]);
      }
      #pragma unroll
      for (int mi=0;mi<2;++mi)
        #pragma unroll
        for (int ni=0;ni<4;++ni)
          acc[mi][ni] = __builtin_amdgcn_mfma_f32_16x16x32_bf16(af[mi], bfm[ni], acc[mi][ni], 0,0,0);
    }
    __syncthreads();
    cur ^= 1;
  }
  #pragma unroll
  for (int mi=0;mi<2;++mi){
    #pragma unroll
    for (int ni=0;ni<4;++ni){
      #pragma unroll
      for (int r=0;r<4;++r){
        int row = m0 + wm*32 + mi*16 + (l>>4)*4 + r;
        int col = n0 + wn*64 + ni*16 + (l&15);
        float v = acc[mi][ni][r];
        if (STORE==0){
          ((u16*)yv)[(size_t)row*OC + col] = f2b(v);
        } else if (STORE==1){
          v = v>=0.f ? v : 0.2f*v;
          int b = row>>LS, s = row&(S-1);
          int oh = s>>LOW, ow = s&(OW-1);
          ((u16*)yv)[((size_t)(b*(OH+2) + oh+1)*(OW+2) + ow+1)*OC + col] = f2b(v);
        } else {
          ((u16*)yv)[((size_t)blockIdx.z*(BB*S) + row)*OC + col] = f2b(v);
        }
      }
    }
  }
  if constexpr (STATS){
    // per-block BN partials: sum/sumsq of bf16-rounded outputs over the 128 rows, per channel
    float* sf  = (float*)As;   // 2048 floats used
    float* sfq = (float*)Bs;
    const int lg = l>>4, c16 = l&15;
    #pragma unroll
    for (int ni=0;ni<4;++ni){
      float s=0.f, ss=0.f;
      #pragma unroll
      for (int mi=0;mi<2;++mi)
        #pragma unroll
        for (int r=0;r<4;++r){
          float vb = b2f(f2b(acc[mi][ni][r]));
          s += vb; ss += vb*vb;
        }
      sf [(wave*4+lg)*64 + ni*16 + c16] = s;
      sfq[(wave*4+lg)*64 + ni*16 + c16] = ss;
    }
    __syncthreads();
    if (tid < 128){
      int wn2 = tid>>6, cl = tid&63;
      float S=0.f, SS=0.f;
      #pragma unroll
      for (int wm2=0;wm2<4;++wm2)
        #pragma unroll
        for (int lg2=0;lg2<4;++lg2){
          int w = wm2*2+wn2;
          S  += sf [(w*4+lg2)*64 + cl];
          SS += sfq[(w*4+lg2)*64 + cl];
        }
      int c = blockIdx.y*128 + wn2*64 + cl;
      stats[(size_t)blockIdx.x*512 + c] = S;
      stats[131072 + (size_t)blockIdx.x*512 + c] = SS;
    }
  }
}

// ============ K-split GEMM, M=128: A bf16 gload_lds dbuf; B bf16 gload_lds OR fp32 reg-convert ============
// P16: partials stored as bf16 (u16) instead of fp32
template<int B_FP32, int P16>
__global__ __launch_bounds__(256) void gemm128_split(
    const u16* __restrict__ A, const void* __restrict__ Bsrc,
    void* __restrict__ part, int K, int kchunk)
{
  __shared__ u16 As[2*128*64];
  __shared__ u16 Bs[2*64*64];
  const int tid = threadIdx.x;
  const int n0 = blockIdx.x*64;
  const int kbase = blockIdx.y*kchunk;
  const int wave = tid>>6, l = tid&63;
  const u16* asrc[4];
  #pragma unroll
  for (int t=0;t<4;++t){
    int unit = tid + t*256, r = unit>>3, us = unit&7;
    asrc[t] = A + (size_t)r*K + (size_t)(us ^ (r&7))*8;
  }
  const float* bf32[4]; int bdst32[4];
  const u16* b16[2];
  if (B_FP32){
    const float* Bf = (const float*)Bsrc;
    #pragma unroll
    for (int t=0;t<4;++t){
      int unit = tid + t*256;
      int r = unit>>4, u4 = unit&15;
      int u = u4>>1, hf = u4&1;
      int us = u ^ (r&7);
      bf32[t] = Bf + (size_t)(n0+r)*K + u4*4;
      bdst32[t] = r*64 + us*8 + hf*4;
    }
  } else {
    const u16* Bb = (const u16*)Bsrc;
    #pragma unroll
    for (int t=0;t<2;++t){
      int unit = tid + t*256, r = unit>>3, us = unit&7;
      b16[t] = Bb + (size_t)(n0+r)*K + (size_t)(us ^ (r&7))*8;
    }
  }

  auto stageA = [&](int half, int k0){
    #pragma unroll
    for (int t=0;t<4;++t)
      GLOAD_LDS16(asrc[t] + k0, &As[half*8192 + (size_t)(t*256 + wave*64)*8]);
  };
  auto stageB16 = [&](int half, int k0){
    #pragma unroll
    for (int t=0;t<2;++t)
      GLOAD_LDS16(b16[t] + k0, &Bs[half*4096 + (size_t)(t*256 + wave*64)*8]);
  };
  float4 breg[4];
  auto loadB32 = [&](int k0){
    #pragma unroll
    for (int t=0;t<4;++t) breg[t] = *(const float4*)(bf32[t] + k0);
  };
  auto writeB32 = [&](int half){
    #pragma unroll
    for (int t=0;t<4;++t){
      short4v o; o[0]=(short)f2b(breg[t].x); o[1]=(short)f2b(breg[t].y);
      o[2]=(short)f2b(breg[t].z); o[3]=(short)f2b(breg[t].w);
      *(short4v*)(&Bs[half*4096 + bdst32[t]]) = o;
    }
  };

  f32x4 acc[2][4] = {};
  const int NT = kchunk >> 6;
  stageA(0, kbase);
  if (B_FP32){ loadB32(kbase); writeB32(0); } else stageB16(0, kbase);
  __syncthreads();
  int cur = 0;
  for (int t=0;t<NT;++t){
    const int k0 = kbase + t*64;
    if (t+1 < NT){
      stageA(cur^1, k0+64);
      if (B_FP32) loadB32(k0+64);
      else stageB16(cur^1, k0+64);
    }
    #pragma unroll
    for (int kk=0;kk<2;++kk){
      short8 af[2], bfm[4];
      #pragma unroll
      for (int mi=0;mi<2;++mi){
        int row = wave*32 + mi*16 + (l&15);
        int u = (kk*4 + (l>>4)) ^ (row&7);
        af[mi] = *(const short8*)(&As[cur*8192 + row*64 + u*8]);
      }
      #pragma unroll
      for (int ni=0;ni<4;++ni){
        int row = ni*16 + (l&15);
        int u = (kk*4 + (l>>4)) ^ (row&7);
        bfm[ni] = *(const short8*)(&Bs[cur*4096 + row*64 + u*8]);
      }
      #pragma unroll
      for (int mi=0;mi<2;++mi)
        #pragma unroll
        for (int ni=0;ni<4;++ni)
          acc[mi][ni] = __builtin_amdgcn_mfma_f32_16x16x32_bf16(af[mi], bfm[ni], acc[mi][ni], 0,0,0);
    }
    if (B_FP32 && t+1 < NT) writeB32(cur^1);
    __syncthreads();
    cur ^= 1;
  }
  #pragma unroll
  for (int mi=0;mi<2;++mi){
    #pragma unroll
    for (int ni=0;ni<4;++ni){
      #pragma unroll
      for (int r=0;r<4;++r){
        int m = wave*32 + mi*16 + (l>>4)*4 + r;
        int n = n0 + ni*16 + (l&15);
        size_t off = ((size_t)blockIdx.y*128 + m)*4096 + n;
        if (P16) ((u16*)part)[off] = f2b(acc[mi][ni][r]);
        else     ((float*)part)[off] = acc[mi][ni][r];
      }
    }
  }
}

// ============ border zeroing helper ============
template<int Hp, int C>
__device__ __forceinline__ void zb_border(u16* __restrict__ buf, int idx, int count){
  if (idx >= count) return;
  constexpr int NP = 4*Hp - 4;
  constexpr int PC = NP*C;
  int b = idx / PC;
  int rem = idx - b*PC;
  int p = rem >> ilog2c(C);
  int c = rem & (C-1);
  int h, w;
  if (p < Hp){ h = 0; w = p; }
  else if (p < 2*Hp){ h = Hp-1; w = p - Hp; }
  else { int q = p - 2*Hp; h = 1 + (q>>1); w = (q&1) ? (Hp-1) : 0; }
  buf[(((size_t)b*Hp + h)*Hp + w)*C + c] = 0;
}

// reduce 16 bf16 FC partials (y2 region, no overlap) -> relu -> xp0 ch3; + xp1/xp2 border zeroing
__global__ __launch_bounds__(256) void fc_reduce_zb(const u16* __restrict__ part,
                                                    u16* __restrict__ xp0,
                                                    u16* __restrict__ xp1, u16* __restrict__ xp2)
{
  const int blk = blockIdx.x, tid = threadIdx.x;
  if (blk < 2048){
    int idx = blk*256 + tid;
    float s = 0.f;
    #pragma unroll
    for (int i=0;i<16;++i) s += b2f(part[(size_t)i*524288 + idx]);
    float v = fmaxf(s, 0.f);
    int m = idx>>12, n = idx&4095;
    int h = n>>6, w2 = n&63;
    xp0[((size_t)(m*66 + h+1)*66 + w2+1)*4 + 3] = f2b(v);
  } else if (blk < 10496){
    zb_border<34,128>(xp1, (blk-2048)*256 + tid, 2162688);
  } else {
    zb_border<18,256>(xp2, (blk-10496)*256 + tid, 2228224);
  }
}

// reduce 8 fp32 partials of [128][4096] -> Ms
__global__ __launch_bounds__(256) void reduce_ms(const float* __restrict__ part, float* __restrict__ outv)
{
  int idx = blockIdx.x*256 + threadIdx.x;
  float s = 0.f;
  #pragma unroll
  for (int i=0;i<8;++i) s += part[(size_t)i*524288 + idx];
  outv[idx] = s;
}

// fused: reduce NS bf16 partials -> bf16 y, AND per-block BN stats partials
template<int NS, int C>
__global__ __launch_bounds__(256) void reduce_bn(
    const u16* __restrict__ part, u16* __restrict__ y,
    float* __restrict__ stats, int Mblk, int Mtot)
{
  constexpr int CU = C/8, NR = 256/CU, LCU = ilog2c(CU);
  __shared__ float red[NR*C];
  const int cu = threadIdx.x & (CU-1);
  const int rg = threadIdx.x >> LCU;
  const int base = blockIdx.x*Mblk;
  float s[8] = {}, ss[8] = {};
  for (int p = base+rg; p < base+Mblk; p += NR){
    float a8[8];
    #pragma unroll
    for (int j=0;j<8;++j) a8[j]=0.f;
    #pragma unroll
    for (int i=0;i<NS;++i){
      short8 v = *(const short8*)(part + ((size_t)i*Mtot + p)*C + cu*8);
      #pragma unroll
      for (int j=0;j<8;++j) a8[j] += b2f((u16)v[j]);
    }
    u16 o[8];
    #pragma unroll
    for (int j=0;j<8;++j){
      o[j] = f2b(a8[j]);
      float vb = b2f(o[j]);
      s[j]+=vb; ss[j]+=vb*vb;
    }
    *(short8*)(y + (size_t)p*C + cu*8) = *(short8*)o;
  }
  #pragma unroll
  for (int j=0;j<8;++j) red[rg*C + cu*8 + j] = s[j];
  __syncthreads();
  for (int c=threadIdx.x; c<C; c+=256){
    float t=0.f;
    #pragma unroll
    for (int r2=0;r2<NR;++r2) t += red[r2*C+c];
    stats[blockIdx.x*512 + c] = t;
  }
  __syncthreads();
  #pragma unroll
  for (int j=0;j<8;++j) red[rg*C + cu*8 + j] = ss[j];
  __syncthreads();
  for (int c=threadIdx.x; c<C; c+=256){
    float t=0.f;
    #pragma unroll
    for (int r2=0;r2<NR;++r2) t += red[r2*C+c];
    stats[131072 + blockIdx.x*512 + c] = t;
  }
}

// reduce conv5 bf16 partials [32][512][256] -> d_out feat (fp32, permuted) + featb (bf16)
__global__ __launch_bounds__(256) void conv5_reduce(const u16* __restrict__ part,
                                                    float* __restrict__ out, u16* __restrict__ featb)
{
  int idx = blockIdx.x*256 + threadIdx.x;
  float s = 0.f;
  #pragma unroll
  for (int i=0;i<32;++i) s += b2f(part[(size_t)i*131072 + idx]);
  int row = idx>>8, col = idx&255;
  int b = row>>2, sp = row&3;
  out[(size_t)b*1280 + col*4 + sp] = s;
  featb[(size_t)b*1024 + col*4 + sp] = f2b(s);
}

// ============ mega-prologue (heavy repacks first for dispatch-tail balance) ============
template<int IC, int ICP>
__device__ __forceinline__ void repack_dev(const float* __restrict__ w, u16* __restrict__ wt,
                                           int oc, int tid, float* ls){
  for (int i=tid; i<IC*16; i+=256){
    int ic = i>>4, khkw = i&15;
    ls[ic*17+khkw] = w[(size_t)oc*IC*16 + i];
  }
  __syncthreads();
  constexpr int KT = 16*ICP;
  constexpr int LP = ilog2c(ICP);
  for (int k=tid; k<KT; k+=256){
    int khkw = k >> LP, ic = k & (ICP-1);
    float v = (ic<IC) ? ls[ic*17+khkw] : 0.f;
    wt[(size_t)oc*KT + k] = f2b(v);
  }
}

__device__ __forceinline__ void transpose_dev(const float* __restrict__ T, u16* __restrict__ Tt,
                                              int idx, int tid, float* tile){
  int bx = idx & 127, by = idx >> 7;
  int kb = by*32, nb = bx*32;
  int tx = tid&31, ty = tid>>5;
  #pragma unroll
  for (int i=0;i<32;i+=8)
    tile[(ty+i)*33 + tx] = T[(size_t)(kb+ty+i)*4096 + nb+tx];
  __syncthreads();
  #pragma unroll
  for (int i=0;i<32;i+=8)
    Tt[(size_t)(nb+ty+i)*1024 + kb+tx] = f2b(tile[tx*33 + ty+i]);
}

__global__ __launch_bounds__(256) void prep_all(
    const float* __restrict__ w1, const float* __restrict__ w2, const float* __restrict__ w3,
    const float* __restrict__ w4, const float* __restrict__ w5, const float* __restrict__ T,
    const float* __restrict__ wvec, const float* __restrict__ img,
    u16* wt1T, u16* wt2T, u16* wt3T, u16* wt4T, u16* wt5T, u16* Tt, u16* wvb, u16* xp0)
{
  __shared__ float ls[512*17];
  const int blk = blockIdx.x, tid = threadIdx.x;
  if (blk < 512)        repack_dev<256,256>(w4, wt4T, blk, tid, ls);
  else if (blk < 768)   repack_dev<512,512>(w5, wt5T, blk-512, tid, ls);
  else if (blk < 1024)  repack_dev<256,256>(w3, wt3T, blk-768, tid, ls);
  else if (blk < 1280)  repack_dev<128,128>(w2, wt2T, blk-1024, tid, ls);
  else if (blk < 1408)  repack_dev<4,4>(w1, wt1T, blk-1280, tid, ls);
  else if (blk < 5504)  transpose_dev(T, Tt, blk-1408, tid, ls);
  else if (blk < 7552){ int i = (blk-5504)*256 + tid; wvb[i] = f2b(wvec[i]); }
  else if (blk < 9600){
    int idx = (blk-7552)*256 + tid;
    int b = idx>>12, s = idx&4095;
    int h = s>>6, w = s&63;
    short4v o;
    o[0] = (short)f2b(img[(size_t)(b*3+0)*4096 + s]);
    o[1] = (short)f2b(img[(size_t)(b*3+1)*4096 + s]);
    o[2] = (short)f2b(img[(size_t)(b*3+2)*4096 + s]);
    o[3] = 0;
    *(short4v*)(xp0 + ((size_t)(b*66 + h+1)*66 + w+1)*4) = o;
  } else {
    zb_border<66,4>(xp0, (blk-9600)*256 + tid, 133120);
  }
}

// ============ BN finalize (separate dispatch = coherence fence) ============
template<int C>
__global__ __launch_bounds__(C) void bn_finalize(float* __restrict__ stats, const float* __restrict__ g,
                                                 const float* __restrict__ be, float cnt){
  int c = threadIdx.x;
  float s=0.f, ss=0.f;
  for (int b=0;b<256;++b){ s += stats[b*512+c]; ss += stats[131072 + b*512+c]; }
  float m = s/cnt;
  float var = ss/cnt - m*m;
  float A = rsqrtf(var + 1e-5f)*g[c];
  stats[262144 + c] = A;
  stats[262144 + 512 + c] = be[c] - m*A;
}

template<int C, int OH>
__device__ __forceinline__ void bn_apply_body(const u16* __restrict__ y, const float* __restrict__ stats,
                                              u16* __restrict__ xp, int idx){
  constexpr int S = OH*OH, LS = ilog2c(S), LOW = ilog2c(OH);
  constexpr int CU = C/8, LCU = ilog2c(CU);
  int p = idx >> LCU, cu = idx & (CU-1);
  short8 v8 = *(const short8*)(y + (size_t)p*C + cu*8);
  const float* Ap = stats + 262144;
  const float* Bp = stats + 262144 + 512;
  u16 o[8];
  #pragma unroll
  for (int j=0;j<8;++j){
    float v = b2f((u16)v8[j])*Ap[cu*8+j] + Bp[cu*8+j];
    o[j] = f2b(v>=0.f ? v : 0.2f*v);
  }
  int b = p>>LS, s = p&(S-1), oh = s>>LOW, ow = s&(OH-1);
  *(short8*)(xp + ((size_t)(b*(OH+2)+oh+1)*(OH+2)+ow+1)*C + cu*8) = *(short8*)o;
}

template<int C, int OH>
__global__ __launch_bounds__(256) void bn_apply(const u16* __restrict__ y, const float* __restrict__ stats,
                                                u16* __restrict__ xp){
  bn_apply_body<C,OH>(y, stats, xp, blockIdx.x*256 + threadIdx.x);
}

// BN2 apply + xp3/xp4 border zeroing (xp1 region dead once this runs)
__global__ __launch_bounds__(256) void bn_apply2_zb(const u16* __restrict__ y, const float* __restrict__ stats,
                                                    u16* __restrict__ xp, u16* xp3, u16* xp4){
  const int blk = blockIdx.x, tid = threadIdx.x;
  if (blk < 4096)       bn_apply_body<256,16>(y, stats, xp, blk*256 + tid);
  else if (blk < 8704)  zb_border<10,256>(xp3, (blk-4096)*256 + tid, 1179648);
  else                  zb_border<6,512>(xp4, (blk-8704)*256 + tid, 1310720);
}

// ============ minibatch discrimination: (i, o-half) grid, 512 threads ============
__global__ __launch_bounds__(512) void mbd_fused(const float* __restrict__ Ms, float* __restrict__ out)
{
  __shared__ float red[4][128];
  const int i = blockIdx.x;
  const int ol = threadIdx.x & 127;
  const int o = blockIdx.y*128 + ol;
  const int jg = threadIdx.x >> 7;      // 0..3, each covers 32 j
  float mi[16];
  #pragma unroll
  for (int u = 0; u < 4; ++u) {
    float4 v = *(const float4*)&Ms[(size_t)i * 4096 + o * 16 + u * 4];
    mi[u*4+0]=v.x; mi[u*4+1]=v.y; mi[u*4+2]=v.z; mi[u*4+3]=v.w;
  }
  float acc = 0.f;
  for (int j = jg*32; j < jg*32 + 32; ++j) {
    float d = 0.f;
    #pragma unroll
    for (int u = 0; u < 4; ++u) {
      float4 v = *(const float4*)&Ms[(size_t)j * 4096 + o * 16 + u * 4];
      d += fabsf(mi[u*4+0]-v.x) + fabsf(mi[u*4+1]-v.y) + fabsf(mi[u*4+2]-v.z) + fabsf(mi[u*4+3]-v.w);
    }
    acc += __expf(-d);
  }
  red[jg][ol] = acc;
  __syncthreads();
  if (jg == 0)
    out[(size_t)i*1280 + 1024 + o] = red[0][ol] + red[1][ol] + red[2][ol] + red[3][ol];
}

__global__ void ws_too_small(float* out, int n){
  int idx = blockIdx.x*256+threadIdx.x;
  if (idx<n) out[idx] = -777.0f;
}

extern "C" void kernel_launch(void* const* d_in, const int* in_sizes, int n_in,
                              void* d_out, int out_size, void* d_ws, size_t ws_size,
                              hipStream_t stream)
{
  const float* image = (const float*)d_in[0];
  const float* wvec  = (const float*)d_in[1];
  const float* fc_w  = (const float*)d_in[2];
  const float* w1    = (const float*)d_in[3];
  const float* w2    = (const float*)d_in[4];
  const float* w3    = (const float*)d_in[5];
  const float* w4    = (const float*)d_in[6];
  const float* w5    = (const float*)d_in[7];
  const float* g2    = (const float*)d_in[8];
  const float* b2    = (const float*)d_in[9];
  const float* g3    = (const float*)d_in[10];
  const float* b3    = (const float*)d_in[11];
  const float* g4    = (const float*)d_in[12];
  const float* b4    = (const float*)d_in[13];
  const float* T     = (const float*)d_in[14];
  float* out = (float*)d_out;
  char* wsb = (char*)d_ws;

  const size_t NEED = 105816064ull;
  if (ws_size < NEED) {
    ws_too_small<<<(out_size + 255)/256, 256, 0, stream>>>(out, out_size);
    return;
  }

  // region map (lifetime-packed):
  u16* xp1   = (u16*)(wsb + 0);
  u16* y3    = (u16*)(wsb + 0);
  u16* xp3   = (u16*)(wsb + 4194304);
  u16* y4    = (u16*)(wsb + 10747904);
  u16* xp4   = (u16*)(wsb + 12845056);
  float* Ms  = (float*)(wsb + 17563648);
  u16* featb = (u16*)(wsb + 19660800);
  float* stats = (float*)(wsb + 19922944);
  u16* xp2   = (u16*)(wsb + 37879808);
  u16* c4part = (u16*)(wsb + 37879808);        // conv4 bf16 partials [4][2048][512]
  u16* c5part = (u16*)(wsb + 37879808);        // conv5 bf16 partials [32][512][256]
  u16* y2    = (u16*)(wsb + 59113472);
  u16* gpartF = (u16*)(wsb + 59113472);        // FC bf16 partials [16][128][4096] (y2 region)
  float* gpartM = (float*)(wsb + 59113472);    // Ms fp32 partials [8][128][4096] (y2 region)
  u16* c3part = (u16*)(wsb + 59113472);        // conv3 bf16 partials [2][8192][256]
  u16* xp0   = (u16*)(wsb + 75890688);
  u16* wt1T  = (u16*)(wsb + 84811776);
  u16* wt2T  = (u16*)(wsb + 84844544);
  u16* wt3T  = (u16*)(wsb + 85893120);
  u16* wt4T  = (u16*)(wsb + 87990272);
  u16* wt5T  = (u16*)(wsb + 92184576);
  u16* Tt    = (u16*)(wsb + 96378880);
  u16* wvb   = (u16*)(wsb + 104767488);

  // 1. mega-prologue
  prep_all<<<10120, 256, 0, stream>>>(w1, w2, w3, w4, w5, T, wvec, image,
                                      wt1T, wt2T, wt3T, wt4T, wt5T, Tt, wvb, xp0);

  // 2-3. FC (16-way K-split, bf16 partials in y2 region) -> reduce -> relu -> xp0 ch3 (+ borders)
  gemm128_split<1,1><<<dim3(64,16), 256, 0, stream>>>(wvb, fc_w, gpartF, 4096, 256);
  fc_reduce_zb<<<19200, 256, 0, stream>>>(gpartF, xp0, xp1, xp2);

  // 4. conv1 + lrelu -> xp1 (IC=4 native)
  convmm2<4,128,32,1><<<dim3(1024,1), 512, 0, stream>>>(xp0, wt1T, xp1, nullptr);
  // 5. conv2 -> y2 + BN2 stats partials (epilogue fusion)
  convmm2<128,256,16,0,1,1><<<dim3(256,2), 512, 0, stream>>>(xp1, wt2T, y2, stats);

  // 6-7. BN2 finalize -> apply + xp3/xp4 borders
  bn_finalize<256><<<1, 256, 0, stream>>>(stats, g2, b2, 32768.f);
  bn_apply2_zb<<<13824, 256, 0, stream>>>(y2, stats, xp2, xp3, xp4);

  // 8-11. conv3 (KSPLIT=2, bf16 partials) -> reduce+stats -> finalize -> apply
  convmm2<256,256,8,3,2><<<dim3(64,2,2), 512, 0, stream>>>(xp2, wt3T, c3part, nullptr);
  reduce_bn<2,256><<<256, 256, 0, stream>>>(c3part, y3, stats, 32, 8192);
  bn_finalize<256><<<1, 256, 0, stream>>>(stats, g3, b3, 8192.f);
  bn_apply<256,8><<<1024, 256, 0, stream>>>(y3, stats, xp3);

  // 12-15. conv4 (KSPLIT=4, bf16 partials) -> reduce+stats -> finalize -> apply
  convmm2<256,512,4,3,4><<<dim3(16,4,4), 512, 0, stream>>>(xp3, wt4T, c4part, nullptr);
  reduce_bn<4,512><<<256, 256, 0, stream>>>(c4part, y4, stats, 8, 2048);
  bn_finalize<512><<<1, 512, 0, stream>>>(stats, g4, b4, 2048.f);
  bn_apply<512,4><<<512, 256, 0, stream>>>(y4, stats, xp4);

  // 16-17. conv5 (KSPLIT=32, bf16 partials) -> reduce -> out feat + featb
  convmm2<512,256,2,3,32><<<dim3(4,2,32), 512, 0, stream>>>(xp4, wt5T, c5part, nullptr);
  conv5_reduce<<<512, 256, 0, stream>>>(c5part, out, featb);

  // 18-19. Ms = feat @ T (K-split 8, fp32 partials in y2 region) -> Ms
  gemm128_split<0,0><<<dim3(64,8), 256, 0, stream>>>(featb, Tt, gpartM, 1024, 128);
  reduce_ms<<<2048, 256, 0, stream>>>(gpartM, Ms);

  // 20. mbd (i, o-half) grid
  mbd_fused<<<dim3(128,2), 512, 0, stream>>>(Ms, out);
}